// Round 3
// baseline (395.507 us; speedup 1.0000x reference)
//
#include <hip/hip_runtime.h>
#include <hip/hip_cooperative_groups.h>

// ACT-LSTM forward, MI355X (gfx950).
// I=1024, H=2048, O=1024, 4H=8192, MAX_STEPS=20, thresh=0.99.
//
// Math: straight-through Binarize selects EXACTLY the first halting step t*
// (fp32: x+(0-x)==0 and Sterbenz for x+(1-x)==1), ponder == t*. Data gives
// p ~= sigmoid(1 +- 0.2) ~= 0.73/step -> t* = 1 -> 2 LSTM steps only.
//
// Round-2 post-mortem: passed, 155 us, hbm 566 GB/s (7% peak), VALUBusy 1.8%,
// VGPR=52 -> latency-bound, almost nothing in flight (unroll-2 step loop
// ~1.3 KB/CU in flight vs ~9 KB needed). Fixes this round:
//  - explicit register-array batching (phase A: 24 scalar loads; step loop:
//    16 float4 per wave outstanding)
//  - 1024 blocks @ __launch_bounds__(256,4) (VGPR<=128 -> 4 blocks/CU
//    guaranteed -> coop launch valid), 16 waves/CU
//  - h staged in LDS per block per step, W rows batched in registers

#define NB    1024      // blocks: 4/CU co-residency (VGPR capped at 128)
#define BT    256       // threads/block = 4 waves (wave = gate i,f,g,o)
#define CPB   2         // h-columns owned per block (NB*CPB == H)
#define HDIM  2048
#define IDIM  1024
#define G4    8192      // 4*H
#define MAXS  20

static_assert(NB * CPB == HDIM, "columns must tile H");

__device__ __attribute__((aligned(16))) float g_h[2][HDIM];  // dbuf hidden
__device__ float g_c[HDIM];          // cell state (owner-block access only)
__device__ float g_part[2][NB];      // dbuf halting partials (one per block)

// fallback-path state
__device__ float g_z[G4];            // z = W_ih[:,1:]@x + b_ih + b_hh
__device__ float g_cum;
__device__ int   g_done, g_tstar, g_curbuf;

__device__ __forceinline__ float wave_reduce(float v) {
  #pragma unroll
  for (int off = 32; off; off >>= 1) v += __shfl_xor(v, off, 64);
  return v;  // full 64-lane sum, present on all lanes
}
__device__ __forceinline__ float sigf(float v) {
  return 1.0f / (1.0f + expf(-v));
}
__device__ __forceinline__ float dot4(float4 a, float4 b) {
  return a.x * b.x + a.y * b.y + a.z * b.z + a.w * b.w;
}

// ---------------------------------------------------------------- coop path
__global__ __launch_bounds__(BT, 4) void act_lstm(
    const float* __restrict__ x,      const float* __restrict__ h_in,
    const float* __restrict__ c_in,   const float* __restrict__ W_ih,
    const float* __restrict__ W_hh,   const float* __restrict__ b_ih,
    const float* __restrict__ b_hh,   const float* __restrict__ w_halt,
    const float* __restrict__ b_halt, const float* __restrict__ W_out,
    const float* __restrict__ b_out,  float* __restrict__ out)
{
  cooperative_groups::grid_group grid = cooperative_groups::this_grid();
  const int tid  = threadIdx.x;
  const int w    = tid >> 6;         // wave id == gate id (i,f,g,o)
  const int lane = tid & 63;
  const int j0   = blockIdx.x * CPB; // owned h-columns j0, j0+1
  const int ra   = w * HDIM + j0;    // gate-w rows
  const int rb   = ra + 1;

  // ---- Phase A (once): z = W_ih[:,1:]@x + b_ih + b_hh, batched loads ----
  const float* Wa = W_ih + (size_t)ra * (IDIM + 1);
  const float* Wb = W_ih + (size_t)rb * (IDIM + 1);
  float za = 0.f, zb = 0.f;
  #pragma unroll
  for (int k = 0; k < 2; ++k) {
    float xv[8], va[8], vb[8];                 // 24 loads in flight
    #pragma unroll
    for (int t = 0; t < 8; ++t) {
      const int c = (k * 8 + t) * 64 + lane;   // coalesced
      xv[t] = x[c];
      va[t] = Wa[1 + c];
      vb[t] = Wb[1 + c];
    }
    #pragma unroll
    for (int t = 0; t < 8; ++t) { za += va[t] * xv[t]; zb += vb[t] * xv[t]; }
  }
  za = wave_reduce(za) + b_ih[ra] + b_hh[ra];
  zb = wave_reduce(zb) + b_ih[rb] + b_hh[rb];
  const float w0a = Wa[0], w0b = Wb[0];        // flag column (step 0 only)
  const float bh  = b_halt[0];

  __shared__ float4 hs[HDIM / 4];   // 8 KB: h staged per block per step
  __shared__ float  gsm[4][CPB];    // gate values [gate][local col]
  __shared__ float  pvs[CPB];       // halting contribution of owned cols
  __shared__ float  red[4];         // per-wave reduction partials

  const float4* Whh4 = reinterpret_cast<const float4*>(W_hh);
  const float4* WA4  = Whh4 + (size_t)ra * (HDIM / 4);
  const float4* WB4  = Whh4 + (size_t)rb * (HDIM / 4);

  float cum = 0.f;
  int tstar = MAXS - 1;
  int cur   = 0;

  for (int step = 0; step < MAXS; ++step) {
    cur = step & 1;
    const float4* hsrc = reinterpret_cast<const float4*>(
        step == 0 ? h_in : (const float*)g_h[cur ^ 1]);

    // stage h into LDS (coalesced, 2 float4/thread)
    hs[tid]       = hsrc[tid];
    hs[tid + 256] = hsrc[tid + 256];
    __syncthreads();

    // ---- recurrent dots: 2 rows/wave, 16 float4 W loads in flight ----
    float4 wa[8], wb[8];
    #pragma unroll
    for (int t = 0; t < 8; ++t) {
      const int idx = t * 64 + lane;
      wa[t] = WA4[idx];
      wb[t] = WB4[idx];
    }
    float sa = 0.f, sb = 0.f;
    #pragma unroll
    for (int t = 0; t < 8; ++t) {
      const float4 hv = hs[t * 64 + lane];
      sa += dot4(wa[t], hv);
      sb += dot4(wb[t], hv);
    }
    sa = wave_reduce(sa);
    sb = wave_reduce(sb);
    if (lane == 0) {
      gsm[w][0] = za + (step == 0 ? w0a : 0.f) + sa;
      gsm[w][1] = zb + (step == 0 ? w0b : 0.f) + sb;
    }
    __syncthreads();

    // ---- pointwise cell update for the 2 owned columns ----
    if (tid < CPB) {
      const int j = j0 + tid;
      const float gi = gsm[0][tid], gf = gsm[1][tid];
      const float gg = gsm[2][tid], go = gsm[3][tid];
      const float co = (step == 0) ? c_in[j] : g_c[j];
      const float cn = sigf(gf) * co + sigf(gi) * tanhf(gg);
      const float hn = sigf(go) * tanhf(cn);
      g_c[j]      = cn;
      g_h[cur][j] = hn;
      pvs[tid]    = w_halt[j] * hn;
    }
    __syncthreads();
    if (tid == 0) g_part[cur][blockIdx.x] = pvs[0] + pvs[1];

    grid.sync();

    // ---- identical deterministic halting sum in every block ----
    float ps = g_part[cur][tid]       + g_part[cur][tid + 256]
             + g_part[cur][tid + 512] + g_part[cur][tid + 768];
    ps = wave_reduce(ps);
    if (lane == 0) red[w] = ps;
    __syncthreads();
    cum += sigf((red[0] + red[1]) + (red[2] + red[3]) + bh);
    if (cum >= 0.99f) { tstar = step; break; }  // uniform across grid
  }

  // ---- epilogue: out = W_out @ h[t*] + b_out; h_out; c_out; ponder ----
  __syncthreads();   // all waves done reading red[] before reuse
  const float* hf = g_h[cur];
  {
    const int r = blockIdx.x;                  // one output row per block
    const float4* Wo4 = reinterpret_cast<const float4*>(W_out)
                        + (size_t)r * (HDIM / 4);
    const float4* hf4 = reinterpret_cast<const float4*>(hf);
    const float4 wv0 = Wo4[tid],       wv1 = Wo4[tid + 256];
    const float4 hv0 = hf4[tid],       hv1 = hf4[tid + 256];
    float acc = dot4(wv0, hv0) + dot4(wv1, hv1);
    acc = wave_reduce(acc);
    if (lane == 0) red[w] = acc;
    __syncthreads();
    if (tid == 0) out[r] = (red[0] + red[1]) + (red[2] + red[3]) + b_out[r];
  }
  if (tid < CPB) {
    const int j = j0 + tid;
    out[1024 + j] = hf[j];     // h_out
    out[3072 + j] = g_c[j];    // c_out
  }
  if (blockIdx.x == 0 && tid == CPB) out[5120] = (float)tstar;  // ponder
}

// ------------------------------------------------------------ fallback path
__global__ void fb_init() {
  g_cum = 0.f; g_done = 0; g_tstar = MAXS - 1; g_curbuf = (MAXS - 1) & 1;
}

__global__ __launch_bounds__(BT) void fb_z(
    const float* __restrict__ x, const float* __restrict__ W_ih,
    const float* __restrict__ b_ih, const float* __restrict__ b_hh)
{
  const int row  = blockIdx.x * 4 + (threadIdx.x >> 6);  // 2048 blocks
  const int lane = threadIdx.x & 63;
  const float* Wr = W_ih + (size_t)row * (IDIM + 1);
  float s = 0.f;
  #pragma unroll
  for (int k = 0; k < 2; ++k) {
    float xv[8], wv[8];
    #pragma unroll
    for (int t = 0; t < 8; ++t) {
      const int c = (k * 8 + t) * 64 + lane;
      xv[t] = x[c]; wv[t] = Wr[1 + c];
    }
    #pragma unroll
    for (int t = 0; t < 8; ++t) s += wv[t] * xv[t];
  }
  s = wave_reduce(s);
  if (lane == 0) g_z[row] = s + b_ih[row] + b_hh[row];
}

__global__ __launch_bounds__(BT) void fb_step(int step,
    const float* __restrict__ h_in, const float* __restrict__ c_in,
    const float* __restrict__ W_ih, const float* __restrict__ W_hh,
    const float* __restrict__ w_halt)
{
  if (g_done) return;
  const int tid = threadIdx.x, w = tid >> 6, lane = tid & 63;
  const int j0 = blockIdx.x * CPB;
  const int ra = w * HDIM + j0, rb = ra + 1;
  const int cur = step & 1;
  const float4* hsrc = reinterpret_cast<const float4*>(
      step == 0 ? h_in : (const float*)g_h[cur ^ 1]);
  __shared__ float4 hs[HDIM / 4];
  __shared__ float gsm[4][CPB];
  __shared__ float pvs[CPB];
  hs[tid]       = hsrc[tid];
  hs[tid + 256] = hsrc[tid + 256];
  __syncthreads();
  const float4* Whh4 = reinterpret_cast<const float4*>(W_hh);
  const float4* WA4  = Whh4 + (size_t)ra * (HDIM / 4);
  const float4* WB4  = Whh4 + (size_t)rb * (HDIM / 4);
  float4 wa[8], wb[8];
  #pragma unroll
  for (int t = 0; t < 8; ++t) {
    const int idx = t * 64 + lane;
    wa[t] = WA4[idx]; wb[t] = WB4[idx];
  }
  float sa = 0.f, sb = 0.f;
  #pragma unroll
  for (int t = 0; t < 8; ++t) {
    const float4 hv = hs[t * 64 + lane];
    sa += dot4(wa[t], hv); sb += dot4(wb[t], hv);
  }
  sa = wave_reduce(sa); sb = wave_reduce(sb);
  if (lane == 0) {
    float zza = g_z[ra], zzb = g_z[rb];
    if (step == 0) {
      zza += W_ih[(size_t)ra * (IDIM + 1)];
      zzb += W_ih[(size_t)rb * (IDIM + 1)];
    }
    gsm[w][0] = zza + sa;
    gsm[w][1] = zzb + sb;
  }
  __syncthreads();
  if (tid < CPB) {
    const int j = j0 + tid;
    const float gi = gsm[0][tid], gf = gsm[1][tid];
    const float gg = gsm[2][tid], go = gsm[3][tid];
    const float co = (step == 0) ? c_in[j] : g_c[j];
    const float cn = sigf(gf) * co + sigf(gi) * tanhf(gg);
    const float hn = sigf(go) * tanhf(cn);
    g_c[j]      = cn;
    g_h[cur][j] = hn;
    pvs[tid]    = w_halt[j] * hn;
  }
  __syncthreads();
  if (tid == 0) g_part[cur][blockIdx.x] = pvs[0] + pvs[1];
}

__global__ __launch_bounds__(BT) void fb_check(int step,
    const float* __restrict__ b_halt)
{
  if (g_done) return;
  const int tid = threadIdx.x, w = tid >> 6, lane = tid & 63;
  const int cur = step & 1;
  float ps = g_part[cur][tid]       + g_part[cur][tid + 256]
           + g_part[cur][tid + 512] + g_part[cur][tid + 768];
  ps = wave_reduce(ps);
  __shared__ float sm[4];
  if (lane == 0) sm[w] = ps;
  __syncthreads();
  if (tid == 0) {
    const float cum = g_cum + sigf((sm[0] + sm[1]) + (sm[2] + sm[3]) + b_halt[0]);
    g_cum = cum;
    if (cum >= 0.99f) { g_done = 1; g_tstar = step; g_curbuf = cur; }
  }
}

__global__ __launch_bounds__(BT) void fb_final(
    const float* __restrict__ W_out, const float* __restrict__ b_out,
    float* __restrict__ out)
{
  const int tid = threadIdx.x, w = tid >> 6, lane = tid & 63;
  const int j0 = blockIdx.x * CPB;
  const float* hf = g_h[g_curbuf];
  __shared__ float red[4];
  const int r = blockIdx.x;
  const float4* Wo4 = reinterpret_cast<const float4*>(W_out)
                      + (size_t)r * (HDIM / 4);
  const float4* hf4 = reinterpret_cast<const float4*>(hf);
  const float4 wv0 = Wo4[tid], wv1 = Wo4[tid + 256];
  const float4 hv0 = hf4[tid], hv1 = hf4[tid + 256];
  float acc = dot4(wv0, hv0) + dot4(wv1, hv1);
  acc = wave_reduce(acc);
  if (lane == 0) red[w] = acc;
  __syncthreads();
  if (tid == 0) out[r] = (red[0] + red[1]) + (red[2] + red[3]) + b_out[r];
  if (tid < CPB) {
    const int j = j0 + tid;
    out[1024 + j] = hf[j];
    out[3072 + j] = g_c[j];
  }
  if (blockIdx.x == 0 && tid == CPB) out[5120] = (float)g_tstar;
}

// ------------------------------------------------------------------- launch
extern "C" void kernel_launch(void* const* d_in, const int* in_sizes, int n_in,
                              void* d_out, int out_size, void* d_ws, size_t ws_size,
                              hipStream_t stream) {
  (void)in_sizes; (void)n_in; (void)d_ws; (void)ws_size; (void)out_size;
  const float* x      = (const float*)d_in[0];
  const float* h      = (const float*)d_in[1];
  const float* c      = (const float*)d_in[2];
  const float* W_ih   = (const float*)d_in[3];
  const float* W_hh   = (const float*)d_in[4];
  const float* b_ih   = (const float*)d_in[5];
  const float* b_hh   = (const float*)d_in[6];
  const float* w_halt = (const float*)d_in[7];
  const float* b_halt = (const float*)d_in[8];
  const float* W_out  = (const float*)d_in[9];
  const float* b_out  = (const float*)d_in[10];
  float* out = (float*)d_out;

  void* args[] = {&x, &h, &c, &W_ih, &W_hh, &b_ih, &b_hh,
                  &w_halt, &b_halt, &W_out, &b_out, &out};
  hipError_t err = hipLaunchCooperativeKernel((void*)act_lstm, dim3(NB),
                                              dim3(BT), args, 0, stream);
  if (err != hipSuccess) {
    // non-cooperative fallback: same math, per-step kernels + device flag
    fb_init<<<1, 1, 0, stream>>>();
    fb_z<<<dim3(G4 / 4), dim3(BT), 0, stream>>>(x, W_ih, b_ih, b_hh);
    for (int s = 0; s < MAXS; ++s) {
      fb_step<<<dim3(NB), dim3(BT), 0, stream>>>(s, h, c, W_ih, W_hh, w_halt);
      fb_check<<<dim3(1), dim3(BT), 0, stream>>>(s, b_halt);
    }
    fb_final<<<dim3(NB), dim3(BT), 0, stream>>>(W_out, b_out, out);
  }
}

// Round 4
// 189.881 us; speedup vs baseline: 2.0829x; 2.0829x over previous
//
#include <hip/hip_runtime.h>

// ACT-LSTM forward, MI355X (gfx950).
// I=1024, H=2048, O=1024, 4H=8192, MAX_STEPS=20, thresh=0.99.
//
// Round-3 post-mortem: persistent cooperative kernel is BARRIER-bound, not
// memory-bound (hbm 2.7%, VALU 1.2%, everything idle; 512->1024 blocks made
// grid.sync ~2x more expensive -> 155->262 us). grid.sync on 8 XCDs is a
// software spin barrier with device-scope fences — tens of us per sync.
//
// This round: NO persistent kernel, NO grid.sync. Kernel boundaries in a
// captured graph ARE grid barriers (release/acquire included, ~1-2 us).
// Fixed 21-dispatch sequence:
//   fb_step0                 z-phase (W_ih@[1,x]) fused with step-0 matvec
//   fb_stepN(s), s=1..19     prologue: recompute halt decision for step s-1
//                            from prev dispatch's partials (identical in all
//                            blocks, no atomics); halted -> early return
//   fb_final                 W_out matvec + h/c/ponder writes
// Data gives p ~= sigmoid(1) ~= 0.73/step -> t* = 1: steps 2..19 early-exit.
//
// Straight-through Binarize selects EXACTLY step t* (fp32: x+(0-x)==0,
// Sterbenz for soft+(1-soft)==1 since soft<2), ponder == t*.

#define NB    1024      // blocks; block b owns h-columns {2b, 2b+1}
#define BT    256       // 4 waves; wave w == gate w (i,f,g,o)
#define CPB   2
#define HDIM  2048
#define IDIM  1024
#define G4    8192
#define MAXS  20

static_assert(NB * CPB == HDIM, "columns must tile H");

__device__ __attribute__((aligned(16))) float g_h[2][HDIM];  // dbuf hidden
__device__ float g_c[HDIM];        // cell state (owner-block access only)
__device__ float g_part[2][NB];    // dbuf halting partials (one per block)
__device__ float g_z[G4];          // z = W_ih[:,1:]@x + b_ih + b_hh
__device__ float g_cums[MAXS];     // g_cums[t] = cumulative halt prob after t
__device__ int   g_done, g_tstar, g_curbuf;

__device__ __forceinline__ float wave_reduce(float v) {
  #pragma unroll
  for (int off = 32; off; off >>= 1) v += __shfl_xor(v, off, 64);
  return v;  // full 64-lane sum on all lanes
}
__device__ __forceinline__ float sigf(float v) {
  return 1.0f / (1.0f + expf(-v));
}
__device__ __forceinline__ float dot4(float4 a, float4 b) {
  return a.x * b.x + a.y * b.y + a.z * b.z + a.w * b.w;
}

// ---- shared inner body: recurrent matvec + cell update for one step ------
// hsrc: h vector to consume (global); writes g_h[cur], g_c, g_part[cur].
__device__ __forceinline__ void step_body(
    int cur, bool first, const float4* __restrict__ hsrc,
    const float* __restrict__ c_in, const float* __restrict__ W_ih,
    const float* __restrict__ W_hh, const float* __restrict__ w_halt,
    float za, float zb)   // caller provides z (+flag on step 0) for its rows
{
  const int tid  = threadIdx.x;
  const int w    = tid >> 6;
  const int lane = tid & 63;
  const int j0   = blockIdx.x * CPB;
  const int ra   = w * HDIM + j0;
  const int rb   = ra + 1;

  __shared__ float4 hs[HDIM / 4];   // 8 KB h stage
  __shared__ float  gsm[4][CPB];
  __shared__ float  pvs[CPB];

  hs[tid]       = hsrc[tid];
  hs[tid + 256] = hsrc[tid + 256];
  __syncthreads();

  const float4* Whh4 = reinterpret_cast<const float4*>(W_hh);
  const float4* WA4  = Whh4 + (size_t)ra * (HDIM / 4);
  const float4* WB4  = Whh4 + (size_t)rb * (HDIM / 4);
  float4 wa[8], wb[8];                       // 16 float4 loads in flight
  #pragma unroll
  for (int t = 0; t < 8; ++t) {
    const int idx = t * 64 + lane;
    wa[t] = WA4[idx];
    wb[t] = WB4[idx];
  }
  float sa = 0.f, sb = 0.f;
  #pragma unroll
  for (int t = 0; t < 8; ++t) {
    const float4 hv = hs[t * 64 + lane];
    sa += dot4(wa[t], hv);
    sb += dot4(wb[t], hv);
  }
  sa = wave_reduce(sa);
  sb = wave_reduce(sb);
  if (lane == 0) {
    gsm[w][0] = za + sa;
    gsm[w][1] = zb + sb;
  }
  __syncthreads();

  if (tid < CPB) {
    const int j = j0 + tid;
    const float gi = gsm[0][tid], gf = gsm[1][tid];
    const float gg = gsm[2][tid], go = gsm[3][tid];
    const float co = first ? c_in[j] : g_c[j];
    const float cn = sigf(gf) * co + sigf(gi) * tanhf(gg);
    const float hn = sigf(go) * tanhf(cn);
    g_c[j]      = cn;
    g_h[cur][j] = hn;
    pvs[tid]    = w_halt[j] * hn;
  }
  __syncthreads();
  if (tid == 0) g_part[cur][blockIdx.x] = pvs[0] + pvs[1];
}

// ---- step 0: z-phase (W_ih @ [1,x] + biases) fused with the matvec -------
__global__ __launch_bounds__(BT, 4) void fb_step0(
    const float* __restrict__ x,    const float* __restrict__ h_in,
    const float* __restrict__ c_in, const float* __restrict__ W_ih,
    const float* __restrict__ W_hh, const float* __restrict__ b_ih,
    const float* __restrict__ b_hh, const float* __restrict__ w_halt)
{
  const int tid  = threadIdx.x;
  const int w    = tid >> 6;
  const int lane = tid & 63;
  const int j0   = blockIdx.x * CPB;
  const int ra   = w * HDIM + j0;
  const int rb   = ra + 1;

  if (blockIdx.x == 0 && tid == 0) g_done = 0;   // reset stale state

  const float* Wa = W_ih + (size_t)ra * (IDIM + 1);
  const float* Wb = W_ih + (size_t)rb * (IDIM + 1);
  float za = 0.f, zb = 0.f;
  #pragma unroll
  for (int k = 0; k < 2; ++k) {
    float xv[8], va[8], vb[8];                 // 24 loads in flight
    #pragma unroll
    for (int t = 0; t < 8; ++t) {
      const int c = (k * 8 + t) * 64 + lane;
      xv[t] = x[c];
      va[t] = Wa[1 + c];
      vb[t] = Wb[1 + c];
    }
    #pragma unroll
    for (int t = 0; t < 8; ++t) { za += va[t] * xv[t]; zb += vb[t] * xv[t]; }
  }
  za = wave_reduce(za) + b_ih[ra] + b_hh[ra];
  zb = wave_reduce(zb) + b_ih[rb] + b_hh[rb];
  if (lane == 0) {           // persist for steps 1..19
    g_z[ra] = za;
    g_z[rb] = zb;
  }
  step_body(/*cur=*/0, /*first=*/true,
            reinterpret_cast<const float4*>(h_in), c_in, W_ih, W_hh, w_halt,
            za + Wa[0], zb + Wb[0]);           // + flag column on step 0
}

// ---- steps 1..19: halt-check prologue + matvec ---------------------------
__global__ __launch_bounds__(BT, 4) void fb_stepN(int step,
    const float* __restrict__ c_in, const float* __restrict__ W_ih,
    const float* __restrict__ W_hh, const float* __restrict__ w_halt,
    const float* __restrict__ b_halt)
{
  if (g_done) return;                          // uniform scalar load

  const int tid  = threadIdx.x;
  const int w    = tid >> 6;
  const int lane = tid & 63;
  const int prev = (step - 1) & 1;

  // halting decision for step-1: identical deterministic sum in every block
  __shared__ float red[4];
  {
    float ps = g_part[prev][tid]       + g_part[prev][tid + 256]
             + g_part[prev][tid + 512] + g_part[prev][tid + 768];
    ps = wave_reduce(ps);
    if (lane == 0) red[w] = ps;
    __syncthreads();
    const float ssum = (red[0] + red[1]) + (red[2] + red[3]);
    const float p    = sigf(ssum + b_halt[0]);
    const float cum  = (step >= 2 ? g_cums[step - 2] : 0.f) + p;
    if (blockIdx.x == 0 && tid == 0) g_cums[step - 1] = cum;
    if (cum >= 0.99f) {                        // same branch in every block
      if (blockIdx.x == 0 && tid == 0) {
        g_done = 1; g_tstar = step - 1; g_curbuf = prev;
      }
      return;
    }
  }
  __syncthreads();   // red[] reuse safety inside step_body's shared arrays

  const int ra = w * HDIM + blockIdx.x * CPB;
  const float za = (lane == 0) ? g_z[ra]     : 0.f;   // only lane 0's is used
  const float zb = (lane == 0) ? g_z[ra + 1] : 0.f;
  step_body(step & 1, /*first=*/false,
            reinterpret_cast<const float4*>((const float*)g_h[prev]),
            c_in, W_ih, W_hh, w_halt, za, zb);
}

// ---- epilogue: out = W_out @ h[t*] + b_out; h_out; c_out; ponder ---------
__global__ __launch_bounds__(BT, 4) void fb_final(
    const float* __restrict__ W_out, const float* __restrict__ b_out,
    float* __restrict__ out)
{
  const int tid = threadIdx.x, w = tid >> 6, lane = tid & 63;
  const int j0  = blockIdx.x * CPB;
  // if never halted (or halted exactly at the cap), output is step MAXS-1
  const int curbuf = g_done ? g_curbuf : (MAXS - 1) & 1;
  const int tstar  = g_done ? g_tstar  : (MAXS - 1);
  const float* hf  = g_h[curbuf];

  __shared__ float red[4];
  const int r = blockIdx.x;                    // one output row per block
  const float4* Wo4 = reinterpret_cast<const float4*>(W_out)
                      + (size_t)r * (HDIM / 4);
  const float4* hf4 = reinterpret_cast<const float4*>(hf);
  const float4 wv0 = Wo4[tid], wv1 = Wo4[tid + 256];
  const float4 hv0 = hf4[tid], hv1 = hf4[tid + 256];
  float acc = dot4(wv0, hv0) + dot4(wv1, hv1);
  acc = wave_reduce(acc);
  if (lane == 0) red[w] = acc;
  __syncthreads();
  if (tid == 0) out[r] = (red[0] + red[1]) + (red[2] + red[3]) + b_out[r];

  if (tid < CPB) {
    const int j = j0 + tid;
    out[1024 + j] = hf[j];     // h_out
    out[3072 + j] = g_c[j];    // c_out
  }
  if (blockIdx.x == 0 && tid == CPB) out[5120] = (float)tstar;  // ponder
}

// ------------------------------------------------------------------- launch
extern "C" void kernel_launch(void* const* d_in, const int* in_sizes, int n_in,
                              void* d_out, int out_size, void* d_ws, size_t ws_size,
                              hipStream_t stream) {
  (void)in_sizes; (void)n_in; (void)d_ws; (void)ws_size; (void)out_size;
  const float* x      = (const float*)d_in[0];
  const float* h      = (const float*)d_in[1];
  const float* c      = (const float*)d_in[2];
  const float* W_ih   = (const float*)d_in[3];
  const float* W_hh   = (const float*)d_in[4];
  const float* b_ih   = (const float*)d_in[5];
  const float* b_hh   = (const float*)d_in[6];
  const float* w_halt = (const float*)d_in[7];
  const float* b_halt = (const float*)d_in[8];
  const float* W_out  = (const float*)d_in[9];
  const float* b_out  = (const float*)d_in[10];
  float* out = (float*)d_out;

  fb_step0<<<dim3(NB), dim3(BT), 0, stream>>>(x, h, c, W_ih, W_hh,
                                              b_ih, b_hh, w_halt);
  for (int s = 1; s < MAXS; ++s)
    fb_stepN<<<dim3(NB), dim3(BT), 0, stream>>>(s, c, W_ih, W_hh,
                                                w_halt, b_halt);
  fb_final<<<dim3(NB), dim3(BT), 0, stream>>>(W_out, b_out, out);
}

// Round 5
// 167.717 us; speedup vs baseline: 2.3582x; 1.1322x over previous
//
#include <hip/hip_runtime.h>

// ACT-LSTM forward, MI355X (gfx950).
// I=1024, H=2048, O=1024, 4H=8192, MAX_STEPS=20, thresh=0.99.
//
// Round-4 post-mortem: 21-dispatch chain passed at 190 us. All our kernels
// are <40 us (top-5 = harness 268MB ws-poison fills). Estimated split:
// ~135 us fixed harness overhead + ~55 us kernels, of which ~30 us is the
// 18 dead early-exit fb_stepN dispatches (~1.5-2 us each).
//
// This round: collapse to 4 dispatches.
//   fb_step0  z = W_ih@[1,x]+biases fused with step-0 W_hh matvec
//   fb_step1  halt-check(step0) prologue + step-1 W_hh matvec
//   fb_tail   1 block: halt-check(step1); if not halted (never for this
//             data), serially run steps 2..19 (correct, dead at runtime)
//   fb_final  W_out matvec + h/c/ponder writes
// Data: p ~= sigmoid(1) ~= 0.73/step -> cum after step1 ~= 1.46 >= 0.99
// (margin 0.47) -> t* = 1, tail early-exits, 2 real matvec steps total.
//
// Straight-through Binarize selects EXACTLY step t* in fp32
// (x+(0-x)==0; Sterbenz gives soft+(1-soft)==1 since soft<2), ponder == t*.

#define NB    1024      // blocks; block b owns h-columns {2b, 2b+1}
#define BT    256       // 4 waves; wave w == gate w (i,f,g,o)
#define CPB   2
#define HDIM  2048
#define IDIM  1024
#define G4    8192
#define MAXS  20

static_assert(NB * CPB == HDIM, "columns must tile H");

__device__ __attribute__((aligned(16))) float g_h[2][HDIM];  // dbuf hidden
__device__ float g_c[HDIM];        // cell state
__device__ float g_part[2][NB];    // dbuf halting partials (one per block)
__device__ float g_z[G4];          // z = W_ih[:,1:]@x + b_ih + b_hh
__device__ float g_cum0;           // cumulative halt prob after step 0
__device__ int   g_done, g_tstar, g_curbuf;

__device__ __forceinline__ float wave_reduce(float v) {
  #pragma unroll
  for (int off = 32; off; off >>= 1) v += __shfl_xor(v, off, 64);
  return v;  // full 64-lane sum on all lanes
}
__device__ __forceinline__ float sigf(float v) {
  return 1.0f / (1.0f + expf(-v));
}
__device__ __forceinline__ float dot4(float4 a, float4 b) {
  return a.x * b.x + a.y * b.y + a.z * b.z + a.w * b.w;
}

// ---- shared inner body: recurrent matvec + cell update for one step ------
__device__ __forceinline__ void step_body(
    int cur, bool first, const float4* __restrict__ hsrc,
    const float* __restrict__ c_in, const float* __restrict__ W_hh,
    const float* __restrict__ w_halt, float za, float zb)
{
  const int tid  = threadIdx.x;
  const int w    = tid >> 6;
  const int lane = tid & 63;
  const int j0   = blockIdx.x * CPB;
  const int ra   = w * HDIM + j0;
  const int rb   = ra + 1;

  __shared__ float4 hs[HDIM / 4];   // 8 KB h stage
  __shared__ float  gsm[4][CPB];
  __shared__ float  pvs[CPB];

  hs[tid]       = hsrc[tid];
  hs[tid + 256] = hsrc[tid + 256];
  __syncthreads();

  const float4* Whh4 = reinterpret_cast<const float4*>(W_hh);
  const float4* WA4  = Whh4 + (size_t)ra * (HDIM / 4);
  const float4* WB4  = Whh4 + (size_t)rb * (HDIM / 4);
  float4 wa[8], wb[8];                       // 16 float4 loads in flight
  #pragma unroll
  for (int t = 0; t < 8; ++t) {
    const int idx = t * 64 + lane;
    wa[t] = WA4[idx];
    wb[t] = WB4[idx];
  }
  float sa = 0.f, sb = 0.f;
  #pragma unroll
  for (int t = 0; t < 8; ++t) {
    const float4 hv = hs[t * 64 + lane];
    sa += dot4(wa[t], hv);
    sb += dot4(wb[t], hv);
  }
  sa = wave_reduce(sa);
  sb = wave_reduce(sb);
  if (lane == 0) {
    gsm[w][0] = za + sa;
    gsm[w][1] = zb + sb;
  }
  __syncthreads();

  if (tid < CPB) {
    const int j = j0 + tid;
    const float gi = gsm[0][tid], gf = gsm[1][tid];
    const float gg = gsm[2][tid], go = gsm[3][tid];
    const float co = first ? c_in[j] : g_c[j];
    const float cn = sigf(gf) * co + sigf(gi) * tanhf(gg);
    const float hn = sigf(go) * tanhf(cn);
    g_c[j]      = cn;
    g_h[cur][j] = hn;
    pvs[tid]    = w_halt[j] * hn;
  }
  __syncthreads();
  if (tid == 0) g_part[cur][blockIdx.x] = pvs[0] + pvs[1];
}

// ---- dispatch 1: z-phase fused with step-0 matvec ------------------------
__global__ __launch_bounds__(BT, 4) void fb_step0(
    const float* __restrict__ x,    const float* __restrict__ h_in,
    const float* __restrict__ c_in, const float* __restrict__ W_ih,
    const float* __restrict__ W_hh, const float* __restrict__ b_ih,
    const float* __restrict__ b_hh, const float* __restrict__ w_halt)
{
  const int tid  = threadIdx.x;
  const int w    = tid >> 6;
  const int lane = tid & 63;
  const int j0   = blockIdx.x * CPB;
  const int ra   = w * HDIM + j0;
  const int rb   = ra + 1;

  if (blockIdx.x == 0 && tid == 0) g_done = 0;   // reset stale state

  const float* Wa = W_ih + (size_t)ra * (IDIM + 1);
  const float* Wb = W_ih + (size_t)rb * (IDIM + 1);
  float za = 0.f, zb = 0.f;
  #pragma unroll
  for (int k = 0; k < 2; ++k) {
    float xv[8], va[8], vb[8];                 // 24 loads in flight
    #pragma unroll
    for (int t = 0; t < 8; ++t) {
      const int c = (k * 8 + t) * 64 + lane;
      xv[t] = x[c];
      va[t] = Wa[1 + c];
      vb[t] = Wb[1 + c];
    }
    #pragma unroll
    for (int t = 0; t < 8; ++t) { za += va[t] * xv[t]; zb += vb[t] * xv[t]; }
  }
  za = wave_reduce(za) + b_ih[ra] + b_hh[ra];
  zb = wave_reduce(zb) + b_ih[rb] + b_hh[rb];
  if (lane == 0) {           // persist for steps 1..19
    g_z[ra] = za;
    g_z[rb] = zb;
  }
  step_body(/*cur=*/0, /*first=*/true,
            reinterpret_cast<const float4*>(h_in), c_in, W_hh, w_halt,
            za + Wa[0], zb + Wb[0]);           // + flag column on step 0
}

// ---- dispatch 2: halt-check(step0) + step-1 matvec -----------------------
__global__ __launch_bounds__(BT, 4) void fb_step1(
    const float* __restrict__ c_in, const float* __restrict__ W_hh,
    const float* __restrict__ w_halt, const float* __restrict__ b_halt)
{
  const int tid  = threadIdx.x;
  const int w    = tid >> 6;
  const int lane = tid & 63;

  // halt decision for step 0: identical deterministic sum in every block
  __shared__ float red[4];
  float ps = g_part[0][tid]       + g_part[0][tid + 256]
           + g_part[0][tid + 512] + g_part[0][tid + 768];
  ps = wave_reduce(ps);
  if (lane == 0) red[w] = ps;
  __syncthreads();
  const float p0 = sigf((red[0] + red[1]) + (red[2] + red[3]) + b_halt[0]);
  if (blockIdx.x == 0 && tid == 0) g_cum0 = p0;
  if (p0 >= 0.99f) {                           // uniform across whole grid
    if (blockIdx.x == 0 && tid == 0) { g_done = 1; g_tstar = 0; g_curbuf = 0; }
    return;
  }
  __syncthreads();

  const int ra = w * HDIM + blockIdx.x * CPB;
  const float za = (lane == 0) ? g_z[ra]     : 0.f;   // only lane0's used
  const float zb = (lane == 0) ? g_z[ra + 1] : 0.f;
  step_body(/*cur=*/1, /*first=*/false,
            reinterpret_cast<const float4*>((const float*)g_h[0]),
            c_in, W_hh, w_halt, za, zb);
}

// ---- dispatch 3: halt-check(step1) + dead serial fallback (1 block) ------
__global__ __launch_bounds__(BT) void fb_tail(
    const float* __restrict__ W_hh, const float* __restrict__ w_halt,
    const float* __restrict__ b_halt)
{
  if (g_done) return;                          // halted at step 0
  const int tid  = threadIdx.x;
  const int w    = tid >> 6;
  const int lane = tid & 63;
  const float bh = b_halt[0];

  __shared__ float red[4];
  float ps = g_part[1][tid]       + g_part[1][tid + 256]
           + g_part[1][tid + 512] + g_part[1][tid + 768];
  ps = wave_reduce(ps);
  if (lane == 0) red[w] = ps;
  __syncthreads();
  float cum = g_cum0 + sigf((red[0] + red[1]) + (red[2] + red[3]) + bh);
  if (cum >= 0.99f) {                          // the runtime path
    if (tid == 0) { g_done = 1; g_tstar = 1; g_curbuf = 1; }
    return;
  }

  // ---- never executed for this data: steps 2..19 serially, one block ----
  __shared__ float hs2[HDIM];
  int tstar = -1;
  for (int s = 2; s < MAXS; ++s) {
    const float* hp = g_h[(s - 1) & 1];
    __syncthreads();
    for (int i = tid; i < HDIM; i += BT) hs2[i] = hp[i];
    __syncthreads();
    float psum = 0.f;
    for (int k = 0; k < HDIM / BT; ++k) {
      const int j = tid + k * BT;
      float gs[4];
      #pragma unroll
      for (int gq = 0; gq < 4; ++gq) {
        const float* Wr = W_hh + (size_t)(gq * HDIM + j) * HDIM;
        float acc = 0.f;
        for (int t = 0; t < HDIM; ++t) acc += Wr[t] * hs2[t];
        gs[gq] = g_z[gq * HDIM + j] + acc;
      }
      const float cn = sigf(gs[1]) * g_c[j] + sigf(gs[0]) * tanhf(gs[2]);
      const float hn = sigf(gs[3]) * tanhf(cn);
      g_c[j] = cn;
      g_h[s & 1][j] = hn;
      psum += w_halt[j] * hn;
    }
    __syncthreads();
    psum = wave_reduce(psum);
    if (lane == 0) red[w] = psum;
    __syncthreads();
    cum += sigf((red[0] + red[1]) + (red[2] + red[3]) + bh);
    if (cum >= 0.99f) { tstar = s; break; }
  }
  if (tid == 0) {
    const int t = (tstar >= 0) ? tstar : (MAXS - 1);
    g_done = 1; g_tstar = t; g_curbuf = t & 1;
  }
}

// ---- dispatch 4: out = W_out @ h[t*] + b_out; h_out; c_out; ponder -------
__global__ __launch_bounds__(BT, 4) void fb_final(
    const float* __restrict__ W_out, const float* __restrict__ b_out,
    float* __restrict__ out)
{
  const int tid = threadIdx.x, w = tid >> 6, lane = tid & 63;
  const int j0  = blockIdx.x * CPB;
  const int curbuf = g_curbuf;                 // always set by step1/tail
  const int tstar  = g_tstar;
  const float* hf  = g_h[curbuf];

  __shared__ float red[4];
  const int r = blockIdx.x;                    // one output row per block
  const float4* Wo4 = reinterpret_cast<const float4*>(W_out)
                      + (size_t)r * (HDIM / 4);
  const float4* hf4 = reinterpret_cast<const float4*>(hf);
  const float4 wv0 = Wo4[tid], wv1 = Wo4[tid + 256];
  const float4 hv0 = hf4[tid], hv1 = hf4[tid + 256];
  float acc = dot4(wv0, hv0) + dot4(wv1, hv1);
  acc = wave_reduce(acc);
  if (lane == 0) red[w] = acc;
  __syncthreads();
  if (tid == 0) out[r] = (red[0] + red[1]) + (red[2] + red[3]) + b_out[r];

  if (tid < CPB) {
    const int j = j0 + tid;
    out[1024 + j] = hf[j];     // h_out
    out[3072 + j] = g_c[j];    // c_out
  }
  if (blockIdx.x == 0 && tid == CPB) out[5120] = (float)tstar;  // ponder
}

// ------------------------------------------------------------------- launch
extern "C" void kernel_launch(void* const* d_in, const int* in_sizes, int n_in,
                              void* d_out, int out_size, void* d_ws, size_t ws_size,
                              hipStream_t stream) {
  (void)in_sizes; (void)n_in; (void)d_ws; (void)ws_size; (void)out_size;
  const float* x      = (const float*)d_in[0];
  const float* h      = (const float*)d_in[1];
  const float* c      = (const float*)d_in[2];
  const float* W_ih   = (const float*)d_in[3];
  const float* W_hh   = (const float*)d_in[4];
  const float* b_ih   = (const float*)d_in[5];
  const float* b_hh   = (const float*)d_in[6];
  const float* w_halt = (const float*)d_in[7];
  const float* b_halt = (const float*)d_in[8];
  const float* W_out  = (const float*)d_in[9];
  const float* b_out  = (const float*)d_in[10];
  float* out = (float*)d_out;

  fb_step0<<<dim3(NB), dim3(BT), 0, stream>>>(x, h, c, W_ih, W_hh,
                                              b_ih, b_hh, w_halt);
  fb_step1<<<dim3(NB), dim3(BT), 0, stream>>>(c, W_hh, w_halt, b_halt);
  fb_tail <<<dim3(1),  dim3(BT), 0, stream>>>(W_hh, w_halt, b_halt);
  fb_final<<<dim3(NB), dim3(BT), 0, stream>>>(W_out, b_out, out);
}